// Round 8
// baseline (145.881 us; speedup 1.0000x reference)
//
#include <hip/hip_runtime.h>
#include <hip/hip_fp16.h>

#define NUSERS 100000
#define NITEMS 50000
#define EMB 64
#define BROWS 1024      // rows per bucket
#define CHUNK 4096      // edges per block in bucket passes
#define MAXB 128        // max buckets (user: 98, item: 49)
#define CAP  16384      // padded bucket capacity (expected ~12.3K, 37 sigma headroom)
#define DMAX 64         // degree clamp for the degree-order counting sort
#define NB_U ((NUSERS + BROWS - 1) / BROWS)   // 98
#define NB_I ((NITEMS + BROWS - 1) / BROWS)   // 49

// packed pair: (local_row << 20) | col   (local_row < 1024, col < 2^17)

// ---- bucketed scatter with direct atomic slot allocation ----
__global__ void bscatter2_kernel(const int* __restrict__ rowU, const int* __restrict__ rowI,
                                 unsigned* __restrict__ bcntU, unsigned* __restrict__ bcntI,
                                 unsigned* __restrict__ pairsU, unsigned* __restrict__ pairsI,
                                 int EU, int EI, int gbU) {
    __shared__ unsigned h[MAXB];
    __shared__ unsigned base[MAXB];
    const int* row; const int* col; unsigned* bcnt; unsigned* pairs; int E, blk, nb;
    if ((int)blockIdx.x < gbU) { row = rowU; col = rowU + EU; bcnt = bcntU; pairs = pairsU; E = EU; blk = blockIdx.x; nb = NB_U; }
    else                       { row = rowI; col = rowI + EI; bcnt = bcntI; pairs = pairsI; E = EI; blk = blockIdx.x - gbU; nb = NB_I; }
    int t = threadIdx.x;
    for (int i = t; i < nb; i += blockDim.x) h[i] = 0;
    __syncthreads();
    int lo = blk * CHUNK, hi = min(lo + CHUNK, E);
    for (int i = lo + t; i < hi; i += blockDim.x)
        atomicAdd(&h[row[i] >> 10], 1u);
    __syncthreads();
    for (int i = t; i < nb; i += blockDim.x) {
        unsigned cnt = h[i];
        base[i] = cnt ? ((unsigned)i * CAP + atomicAdd(&bcnt[i], cnt)) : 0u;
        h[i] = 0;
    }
    __syncthreads();
    for (int i = lo + t; i < hi; i += blockDim.x) {
        int r = row[i];
        int b = r >> 10;
        unsigned p = base[b] + atomicAdd(&h[b], 1u);
        pairs[p] = ((unsigned)(r & 1023) << 20) | (unsigned)col[i];
    }
}

// ---- fused per-bucket: degree + inv + offset alloc + fine fill + degree-order ----
__global__ void bprep_kernel(const unsigned* __restrict__ bcntU, const unsigned* __restrict__ bcntI,
                             const unsigned* __restrict__ pairsU, const unsigned* __restrict__ pairsI,
                             uint2* __restrict__ odU, uint2* __restrict__ odI,
                             float* __restrict__ invU, float* __restrict__ invI,
                             int* __restrict__ colsU, int* __restrict__ colsI,
                             unsigned* __restrict__ totU, unsigned* __restrict__ totI,
                             unsigned* __restrict__ rordU, unsigned* __restrict__ rordI) {
    __shared__ unsigned d[BROWS];
    __shared__ unsigned c[BROWS];
    __shared__ unsigned sh[256];
    __shared__ unsigned dh[DMAX];
    __shared__ unsigned sbase;
    const unsigned* bcnt; const unsigned* pairs; uint2* od; float* inv; int* cols;
    unsigned* tot; unsigned* rord; int n, b;
    if ((int)blockIdx.x < NB_U) { bcnt = bcntU; pairs = pairsU; od = odU; inv = invU; cols = colsU; tot = totU; rord = rordU; n = NUSERS; b = blockIdx.x; }
    else                        { bcnt = bcntI; pairs = pairsI; od = odI; inv = invI; cols = colsI; tot = totI; rord = rordI; n = NITEMS; b = blockIdx.x - NB_U; }
    int t = threadIdx.x;
    int rbase = b * BROWS;
    int nrows = min(BROWS, n - rbase);
    for (int i = t; i < BROWS; i += 256) d[i] = 0;
    if (t < DMAX) dh[t] = 0;
    __syncthreads();
    unsigned lo = (unsigned)b * CAP, hi = lo + bcnt[b];
    for (unsigned i = lo + t; i < hi; i += 256)
        atomicAdd(&d[pairs[i] >> 20], 1u);
    __syncthreads();
    unsigned v[4], s = 0;
    #pragma unroll
    for (int i = 0; i < 4; i++) { v[i] = d[t * 4 + i]; s += v[i]; }
    sh[t] = s;
    __syncthreads();
    for (int off = 1; off < 256; off <<= 1) {
        unsigned add = (t >= off) ? sh[t - off] : 0u;
        __syncthreads();
        sh[t] += add;
        __syncthreads();
    }
    if (t == 255) sbase = atomicAdd(tot, sh[255]);   // bucket's base in cols[]
    __syncthreads();
    unsigned running = sbase + sh[t] - s;
    #pragma unroll
    for (int i = 0; i < 4; i++) {
        int li = t * 4 + i;
        int idx = rbase + li;
        if (idx < n) {
            od[idx] = make_uint2(running, v[i]);
            inv[idx] = rsqrtf((float)(v[i] + 1u));
            c[li] = running;
            running += v[i];
        }
    }
    __syncthreads();
    // fine fill from padded pairs via LDS cursors
    for (unsigned i = lo + t; i < hi; i += 256) {
        unsigned pk = pairs[i];
        unsigned p = atomicAdd(&c[pk >> 20], 1u);
        cols[p] = (int)(pk & 0xFFFFFu);
    }
    // degree-order permutation (per-bucket counting sort over clamped degree)
    for (int li = t; li < nrows; li += 256)
        atomicAdd(&dh[min(d[li], (unsigned)(DMAX - 1))], 1u);
    __syncthreads();
    if (t == 0) {
        unsigned run = 0;
        for (int i = 0; i < DMAX; i++) { unsigned x = dh[i]; dh[i] = run; run += x; }
    }
    __syncthreads();
    for (int li = t; li < nrows; li += 256) {
        unsigned dg = min(d[li], (unsigned)(DMAX - 1));
        unsigned pos = atomicAdd(&dh[dg], 1u);
        rord[rbase + pos] = (unsigned)(rbase + li);
    }
}

// ---- W*inv[row] -> f16 copies (pre-scaled by source-node norm); overlays dead pairs ----
__global__ void tohalf2_kernel(const float* __restrict__ WU, const float* __restrict__ WI,
                               const float* __restrict__ invU, const float* __restrict__ invI,
                               __half* __restrict__ WhU, __half* __restrict__ WhI) {
    const int totU = NUSERS * EMB / 4;
    const int totI = NITEMS * EMB / 4;
    int i = blockIdx.x * 256 + threadIdx.x;
    const float* W; const float* inv; __half* Wh;
    if (i < totU)             { W = WU; inv = invU; Wh = WhU; }
    else if (i < totU + totI) { i -= totU; W = WI; inv = invI; Wh = WhI; }
    else return;
    int r = i >> 4;                 // 16 float4s per row
    float s = inv[r];
    float4 w = ((const float4*)W)[i];
    __half2 h0 = __floats2half2_rn(w.x * s, w.y * s);
    __half2 h1 = __floats2half2_rn(w.z * s, w.w * s);
    ((__half2*)Wh)[2 * i]     = h0;
    ((__half2*)Wh)[2 * i + 1] = h1;
}

__device__ __forceinline__ void acc8(float* acc, float4 f) {
    const __half2* h = (const __half2*)&f;
    #pragma unroll
    for (int j = 0; j < 4; j++) {
        float2 tv = __half22float2(h[j]);
        acc[2 * j]     += tv.x;
        acc[2 * j + 1] += tv.y;
    }
}

// ---- gather, f16: 8 lanes per row, rows visited in degree-sorted order,
// 4-way unrolled edge loop (4 cols + 4 row loads in flight per group) ----
__global__ void gather2h_kernel(const uint2* __restrict__ odU, const uint2* __restrict__ odI,
                                const unsigned* __restrict__ rordU, const unsigned* __restrict__ rordI,
                                const int* __restrict__ colsU, const int* __restrict__ colsI,
                                const __half* __restrict__ WhU, const __half* __restrict__ WhI,
                                const float* __restrict__ bU, const float* __restrict__ bI,
                                const float* __restrict__ invU, const float* __restrict__ invI,
                                float* __restrict__ outU, float* __restrict__ outI, int ggU) {
    const uint2* od; const unsigned* rord; const int* cols; const __half* Wh;
    const float* bb; const float* inv; float* out; int n, r0;
    if ((int)blockIdx.x < ggU) { od = odU; rord = rordU; cols = colsU; Wh = WhU; bb = bU; inv = invU; out = outU; n = NUSERS; r0 = blockIdx.x * 32; }
    else                       { od = odI; rord = rordI; cols = colsI; Wh = WhI; bb = bI; inv = invI; out = outI; n = NITEMS; r0 = (blockIdx.x - ggU) * 32; }
    int ord = r0 + (threadIdx.x >> 3);
    if (ord >= n) return;
    int r = (int)rord[ord];
    int d8 = threadIdx.x & 7;
    uint2 o = od[r];
    unsigned k = o.x, end = o.x + o.y;
    const __half* wb = Wh + d8 * 8;
    float acc[8] = {0.f, 0.f, 0.f, 0.f, 0.f, 0.f, 0.f, 0.f};
    for (; k + 4 <= end; k += 4) {
        int c0 = cols[k];
        int c1 = cols[k + 1];
        int c2 = cols[k + 2];
        int c3 = cols[k + 3];
        float4 f0 = *(const float4*)(wb + (size_t)c0 * EMB);
        float4 f1 = *(const float4*)(wb + (size_t)c1 * EMB);
        float4 f2 = *(const float4*)(wb + (size_t)c2 * EMB);
        float4 f3 = *(const float4*)(wb + (size_t)c3 * EMB);
        acc8(acc, f0); acc8(acc, f1); acc8(acc, f2); acc8(acc, f3);
    }
    for (; k < end; ++k) {
        int c0 = cols[k];
        float4 f0 = *(const float4*)(wb + (size_t)c0 * EMB);
        acc8(acc, f0);
    }
    // epilogue: out = relu((acc + Wh[r]) * inv_r + b)   (Wh[r]*inv_r = W[r]*inv_r^2)
    float inv_r = inv[r];
    float4 fs = *(const float4*)(Wh + (size_t)r * EMB + d8 * 8);
    float sf[8];
    {
        const __half2* h = (const __half2*)&fs;
        #pragma unroll
        for (int j = 0; j < 4; j++) {
            float2 tv = __half22float2(h[j]);
            sf[2 * j] = tv.x; sf[2 * j + 1] = tv.y;
        }
    }
    const float4 bv0 = *(const float4*)(bb + d8 * 8);
    const float4 bv1 = *(const float4*)(bb + d8 * 8 + 4);
    float4 o0, o1;
    o0.x = fmaxf((acc[0] + sf[0]) * inv_r + bv0.x, 0.f);
    o0.y = fmaxf((acc[1] + sf[1]) * inv_r + bv0.y, 0.f);
    o0.z = fmaxf((acc[2] + sf[2]) * inv_r + bv0.z, 0.f);
    o0.w = fmaxf((acc[3] + sf[3]) * inv_r + bv0.w, 0.f);
    o1.x = fmaxf((acc[4] + sf[4]) * inv_r + bv1.x, 0.f);
    o1.y = fmaxf((acc[5] + sf[5]) * inv_r + bv1.y, 0.f);
    o1.z = fmaxf((acc[6] + sf[6]) * inv_r + bv1.z, 0.f);
    o1.w = fmaxf((acc[7] + sf[7]) * inv_r + bv1.w, 0.f);
    *(float4*)(out + (size_t)r * EMB + d8 * 8)     = o0;
    *(float4*)(out + (size_t)r * EMB + d8 * 8 + 4) = o1;
}

// ---- f32 fallback gather (if workspace too small for f16 copies) ----
__global__ void gather2f_kernel(const uint2* __restrict__ odU, const uint2* __restrict__ odI,
                                const unsigned* __restrict__ rordU, const unsigned* __restrict__ rordI,
                                const int* __restrict__ colsU, const int* __restrict__ colsI,
                                const float* __restrict__ WU, const float* __restrict__ WI,
                                const float* __restrict__ bU, const float* __restrict__ bI,
                                const float* __restrict__ invU, const float* __restrict__ invI,
                                float* __restrict__ outU, float* __restrict__ outI, int ggU) {
    const uint2* od; const unsigned* rord; const int* cols; const float* W;
    const float* bb; const float* inv; float* out; int n, r0;
    if ((int)blockIdx.x < ggU) { od = odU; rord = rordU; cols = colsU; W = WU; bb = bU; inv = invU; out = outU; n = NUSERS; r0 = blockIdx.x * 32; }
    else                       { od = odI; rord = rordI; cols = colsI; W = WI; bb = bI; inv = invI; out = outI; n = NITEMS; r0 = (blockIdx.x - ggU) * 32; }
    int ord = r0 + (threadIdx.x >> 3);
    if (ord >= n) return;
    int r = (int)rord[ord];
    int d8 = threadIdx.x & 7;
    uint2 o = od[r];
    unsigned k = o.x, end = o.x + o.y;
    const float* wb = W + d8 * 8;
    float acc[8] = {0.f, 0.f, 0.f, 0.f, 0.f, 0.f, 0.f, 0.f};
    for (; k < end; ++k) {
        int c0 = cols[k];
        float ic = inv[c0];
        float4 f0 = *(const float4*)(wb + (size_t)c0 * EMB);
        float4 f1 = *(const float4*)(wb + (size_t)c0 * EMB + 4);
        acc[0] += f0.x * ic; acc[1] += f0.y * ic; acc[2] += f0.z * ic; acc[3] += f0.w * ic;
        acc[4] += f1.x * ic; acc[5] += f1.y * ic; acc[6] += f1.z * ic; acc[7] += f1.w * ic;
    }
    float inv_r = inv[r];
    float4 s0 = *(const float4*)(W + (size_t)r * EMB + d8 * 8);
    float4 s1 = *(const float4*)(W + (size_t)r * EMB + d8 * 8 + 4);
    const float4 bv0 = *(const float4*)(bb + d8 * 8);
    const float4 bv1 = *(const float4*)(bb + d8 * 8 + 4);
    float4 o0, o1;
    o0.x = fmaxf((acc[0] + s0.x * inv_r) * inv_r + bv0.x, 0.f);
    o0.y = fmaxf((acc[1] + s0.y * inv_r) * inv_r + bv0.y, 0.f);
    o0.z = fmaxf((acc[2] + s0.z * inv_r) * inv_r + bv0.z, 0.f);
    o0.w = fmaxf((acc[3] + s0.w * inv_r) * inv_r + bv0.w, 0.f);
    o1.x = fmaxf((acc[4] + s1.x * inv_r) * inv_r + bv1.x, 0.f);
    o1.y = fmaxf((acc[5] + s1.y * inv_r) * inv_r + bv1.y, 0.f);
    o1.z = fmaxf((acc[6] + s1.z * inv_r) * inv_r + bv1.z, 0.f);
    o1.w = fmaxf((acc[7] + s1.w * inv_r) * inv_r + bv1.w, 0.f);
    *(float4*)(out + (size_t)r * EMB + d8 * 8)     = o0;
    *(float4*)(out + (size_t)r * EMB + d8 * 8 + 4) = o1;
}

extern "C" void kernel_launch(void* const* d_in, const int* in_sizes, int n_in,
                              void* d_out, int out_size, void* d_ws, size_t ws_size,
                              hipStream_t stream) {
    const int*   ue = (const int*)d_in[0];
    const int*   ie = (const int*)d_in[1];
    const float* Wu = (const float*)d_in[2];
    const float* bu = (const float*)d_in[3];
    const float* Wi = (const float*)d_in[4];
    const float* bi = (const float*)d_in[5];

    const int E_U = in_sizes[0] / 2;
    const int E_I = in_sizes[1] / 2;

    float* out_u = (float*)d_out;
    float* out_i = out_u + (size_t)NUSERS * EMB;

    // workspace layout (4-byte words); Wh overlays the dead pairs region
    unsigned* w       = (unsigned*)d_ws;
    unsigned* bcnt_u  = w;            w += MAXB;     // zeroed
    unsigned* bcnt_i  = w;            w += MAXB;     // zeroed
    unsigned* tot_u   = w;            w += 1;        // zeroed
    unsigned* tot_i   = w;            w += 1;        // zeroed
    uint2*    od_u    = (uint2*)w;    w += 2 * (size_t)NUSERS;
    uint2*    od_i    = (uint2*)w;    w += 2 * (size_t)NITEMS;
    float*    inv_u   = (float*)w;    w += NUSERS;
    float*    inv_i   = (float*)w;    w += NITEMS;
    unsigned* rord_u  = w;            w += NUSERS;
    unsigned* rord_i  = w;            w += NITEMS;
    int*      cols_u  = (int*)w;      w += E_U;
    int*      cols_i  = (int*)w;      w += E_I;
    w += (size_t)(-(intptr_t)(w - (unsigned*)d_ws)) & 3;   // align to 16 B
    // union region: pairs (build phase) / Wh (gather phase)
    unsigned* un      = w;
    unsigned* pairs_u = un;                            // NB_U*CAP words
    unsigned* pairs_i = un + (size_t)NB_U * CAP;       // NB_I*CAP words
    __half*   wh_u    = (__half*)un;                   // NUSERS*EMB halfs
    __half*   wh_i    = (__half*)un + (size_t)NUSERS * EMB;
    size_t un_words_pairs = (size_t)(NB_U + NB_I) * CAP;
    size_t un_words_wh    = (size_t)(NUSERS + NITEMS) * EMB / 2;
    size_t un_words = un_words_pairs > un_words_wh ? un_words_pairs : un_words_wh;
    const size_t need_bytes = (size_t)((char*)(un + un_words) - (char*)d_ws);
    const bool use_half = (ws_size >= need_bytes);

    hipMemsetAsync(bcnt_u, 0, (2 * MAXB + 2) * sizeof(unsigned), stream);

    const int gb_u = (E_U + CHUNK - 1) / CHUNK;  // 293
    const int gb_i = (E_I + CHUNK - 1) / CHUNK;  // 147
    const int gg_u = (NUSERS + 31) / 32;         // 3125
    const int gg_i = (NITEMS + 31) / 32;         // 1563

    bscatter2_kernel<<<gb_u + gb_i, 256, 0, stream>>>(ue, ie, bcnt_u, bcnt_i,
                                                      pairs_u, pairs_i, E_U, E_I, gb_u);
    bprep_kernel    <<<NB_U + NB_I, 256, 0, stream>>>(bcnt_u, bcnt_i, pairs_u, pairs_i,
                                                      od_u, od_i, inv_u, inv_i,
                                                      cols_u, cols_i, tot_u, tot_i,
                                                      rord_u, rord_i);
    if (use_half) {
        const int tot4 = (NUSERS + NITEMS) * EMB / 4;
        tohalf2_kernel <<<(tot4 + 255) / 256, 256, 0, stream>>>(Wu, Wi, inv_u, inv_i, wh_u, wh_i);
        gather2h_kernel<<<gg_u + gg_i, 256, 0, stream>>>(od_u, od_i, rord_u, rord_i,
                                                         cols_u, cols_i, wh_u, wh_i,
                                                         bu, bi, inv_u, inv_i,
                                                         out_u, out_i, gg_u);
    } else {
        gather2f_kernel<<<gg_u + gg_i, 256, 0, stream>>>(od_u, od_i, rord_u, rord_i,
                                                         cols_u, cols_i, Wu, Wi,
                                                         bu, bi, inv_u, inv_i,
                                                         out_u, out_i, gg_u);
    }
}

// Round 9
// 129.731 us; speedup vs baseline: 1.1245x; 1.1245x over previous
//
#include <hip/hip_runtime.h>
#include <hip/hip_fp16.h>

#define NUSERS 100000
#define NITEMS 50000
#define EMB 64
#define BROWS 1024      // rows per bucket
#define CHUNK 4096      // edges per block in bucket passes
#define MAXB 128        // max buckets (user: 98, item: 49)
#define CAP  16384      // padded bucket capacity (expected ~12.3K, 37 sigma headroom)
#define NB_U ((NUSERS + BROWS - 1) / BROWS)   // 98
#define NB_I ((NITEMS + BROWS - 1) / BROWS)   // 49

// packed pair: (local_row << 20) | col   (local_row < 1024, col < 2^17)

// ---- bucketed scatter with direct atomic slot allocation; rows staged in LDS ----
__global__ void bscatter2_kernel(const int* __restrict__ rowU, const int* __restrict__ rowI,
                                 unsigned* __restrict__ bcntU, unsigned* __restrict__ bcntI,
                                 unsigned* __restrict__ pairsU, unsigned* __restrict__ pairsI,
                                 int EU, int EI, int gbU) {
    __shared__ unsigned h[MAXB];
    __shared__ unsigned base[MAXB];
    __shared__ int rstage[CHUNK];
    const int* row; const int* col; unsigned* bcnt; unsigned* pairs; int E, blk, nb;
    if ((int)blockIdx.x < gbU) { row = rowU; col = rowU + EU; bcnt = bcntU; pairs = pairsU; E = EU; blk = blockIdx.x; nb = NB_U; }
    else                       { row = rowI; col = rowI + EI; bcnt = bcntI; pairs = pairsI; E = EI; blk = blockIdx.x - gbU; nb = NB_I; }
    int t = threadIdx.x;
    for (int i = t; i < nb; i += blockDim.x) h[i] = 0;
    __syncthreads();
    int lo = blk * CHUNK, hi = min(lo + CHUNK, E);
    for (int i = lo + t; i < hi; i += blockDim.x) {
        int r = row[i];
        rstage[i - lo] = r;
        atomicAdd(&h[r >> 10], 1u);
    }
    __syncthreads();
    for (int i = t; i < nb; i += blockDim.x) {
        unsigned cnt = h[i];
        base[i] = cnt ? ((unsigned)i * CAP + atomicAdd(&bcnt[i], cnt)) : 0u;
        h[i] = 0;
    }
    __syncthreads();
    for (int i = lo + t; i < hi; i += blockDim.x) {
        int r = rstage[i - lo];
        int b = r >> 10;
        unsigned p = base[b] + atomicAdd(&h[b], 1u);
        pairs[p] = ((unsigned)(r & 1023) << 20) | (unsigned)col[i];
    }
}

// ---- fused per-bucket: degree count + inv + block scan + atomic base alloc + fine fill ----
__global__ void bprep_kernel(const unsigned* __restrict__ bcntU, const unsigned* __restrict__ bcntI,
                             const unsigned* __restrict__ pairsU, const unsigned* __restrict__ pairsI,
                             uint2* __restrict__ odU, uint2* __restrict__ odI,
                             float* __restrict__ invU, float* __restrict__ invI,
                             int* __restrict__ colsU, int* __restrict__ colsI,
                             unsigned* __restrict__ totU, unsigned* __restrict__ totI) {
    __shared__ unsigned d[BROWS];
    __shared__ unsigned c[BROWS];
    __shared__ unsigned sh[256];
    __shared__ unsigned sbase;
    const unsigned* bcnt; const unsigned* pairs; uint2* od; float* inv; int* cols; unsigned* tot; int n, b;
    if ((int)blockIdx.x < NB_U) { bcnt = bcntU; pairs = pairsU; od = odU; inv = invU; cols = colsU; tot = totU; n = NUSERS; b = blockIdx.x; }
    else                        { bcnt = bcntI; pairs = pairsI; od = odI; inv = invI; cols = colsI; tot = totI; n = NITEMS; b = blockIdx.x - NB_U; }
    int t = threadIdx.x;
    int rbase = b * BROWS;
    for (int i = t; i < BROWS; i += 256) d[i] = 0;
    __syncthreads();
    unsigned lo = (unsigned)b * CAP, hi = lo + bcnt[b];
    for (unsigned i = lo + t; i < hi; i += 256)
        atomicAdd(&d[pairs[i] >> 20], 1u);
    __syncthreads();
    unsigned v[4], s = 0;
    #pragma unroll
    for (int i = 0; i < 4; i++) { v[i] = d[t * 4 + i]; s += v[i]; }
    sh[t] = s;
    __syncthreads();
    for (int off = 1; off < 256; off <<= 1) {
        unsigned add = (t >= off) ? sh[t - off] : 0u;
        __syncthreads();
        sh[t] += add;
        __syncthreads();
    }
    if (t == 255) sbase = atomicAdd(tot, sh[255]);   // bucket's base in cols[]
    __syncthreads();
    unsigned running = sbase + sh[t] - s;
    #pragma unroll
    for (int i = 0; i < 4; i++) {
        int li = t * 4 + i;
        int idx = rbase + li;
        if (idx < n) {
            od[idx] = make_uint2(running, v[i]);
            inv[idx] = rsqrtf((float)(v[i] + 1u));
            c[li] = running;
            running += v[i];
        }
    }
    __syncthreads();
    for (unsigned i = lo + t; i < hi; i += 256) {
        unsigned pk = pairs[i];
        unsigned p = atomicAdd(&c[pk >> 20], 1u);
        cols[p] = (int)(pk & 0xFFFFFu);
    }
}

// ---- W*inv[row] -> f16 copies (pre-scaled by source-node norm); overlays dead pairs ----
__global__ void tohalf2_kernel(const float* __restrict__ WU, const float* __restrict__ WI,
                               const float* __restrict__ invU, const float* __restrict__ invI,
                               __half* __restrict__ WhU, __half* __restrict__ WhI) {
    const int totU = NUSERS * EMB / 4;
    const int totI = NITEMS * EMB / 4;
    int i = blockIdx.x * 256 + threadIdx.x;
    const float* W; const float* inv; __half* Wh;
    if (i < totU)             { W = WU; inv = invU; Wh = WhU; }
    else if (i < totU + totI) { i -= totU; W = WI; inv = invI; Wh = WhI; }
    else return;
    int r = i >> 4;                 // 16 float4s per row
    float s = inv[r];
    float4 w = ((const float4*)W)[i];
    __half2 h0 = __floats2half2_rn(w.x * s, w.y * s);
    __half2 h1 = __floats2half2_rn(w.z * s, w.w * s);
    ((__half2*)Wh)[2 * i]     = h0;
    ((__half2*)Wh)[2 * i + 1] = h1;
}

__device__ __forceinline__ void acc8(float* acc, float4 f) {
    const __half2* h = (const __half2*)&f;
    #pragma unroll
    for (int j = 0; j < 4; j++) {
        float2 tv = __half22float2(h[j]);
        acc[2 * j]     += tv.x;
        acc[2 * j + 1] += tv.y;
    }
}

// ---- gather, f16: 8 lanes per row (d8 = 16B slice), 8 sequential rows per wave,
// 4-way unrolled edge loop (4 cols + 4 row loads in flight per group) ----
__global__ void gather2h_kernel(const uint2* __restrict__ odU, const uint2* __restrict__ odI,
                                const int* __restrict__ colsU, const int* __restrict__ colsI,
                                const __half* __restrict__ WhU, const __half* __restrict__ WhI,
                                const float* __restrict__ bU, const float* __restrict__ bI,
                                const float* __restrict__ invU, const float* __restrict__ invI,
                                float* __restrict__ outU, float* __restrict__ outI, int ggU) {
    const uint2* od; const int* cols; const __half* Wh; const float* bb; const float* inv;
    float* out; int n, r0;
    if ((int)blockIdx.x < ggU) { od = odU; cols = colsU; Wh = WhU; bb = bU; inv = invU; out = outU; n = NUSERS; r0 = blockIdx.x * 32; }
    else                       { od = odI; cols = colsI; Wh = WhI; bb = bI; inv = invI; out = outI; n = NITEMS; r0 = (blockIdx.x - ggU) * 32; }
    int r = r0 + (threadIdx.x >> 3);
    if (r >= n) return;
    int d8 = threadIdx.x & 7;
    uint2 o = od[r];
    unsigned k = o.x, end = o.x + o.y;
    const __half* wb = Wh + d8 * 8;
    float acc[8] = {0.f, 0.f, 0.f, 0.f, 0.f, 0.f, 0.f, 0.f};
    for (; k + 4 <= end; k += 4) {
        int c0 = cols[k];
        int c1 = cols[k + 1];
        int c2 = cols[k + 2];
        int c3 = cols[k + 3];
        float4 f0 = *(const float4*)(wb + (size_t)c0 * EMB);
        float4 f1 = *(const float4*)(wb + (size_t)c1 * EMB);
        float4 f2 = *(const float4*)(wb + (size_t)c2 * EMB);
        float4 f3 = *(const float4*)(wb + (size_t)c3 * EMB);
        acc8(acc, f0); acc8(acc, f1); acc8(acc, f2); acc8(acc, f3);
    }
    for (; k < end; ++k) {
        int c0 = cols[k];
        float4 f0 = *(const float4*)(wb + (size_t)c0 * EMB);
        acc8(acc, f0);
    }
    // epilogue: out = relu((acc + Wh[r]) * inv_r + b)   (Wh[r]*inv_r = W[r]*inv_r^2)
    float inv_r = inv[r];
    float4 fs = *(const float4*)(Wh + (size_t)r * EMB + d8 * 8);
    float sf[8];
    {
        const __half2* h = (const __half2*)&fs;
        #pragma unroll
        for (int j = 0; j < 4; j++) {
            float2 tv = __half22float2(h[j]);
            sf[2 * j] = tv.x; sf[2 * j + 1] = tv.y;
        }
    }
    const float4 bv0 = *(const float4*)(bb + d8 * 8);
    const float4 bv1 = *(const float4*)(bb + d8 * 8 + 4);
    float4 o0, o1;
    o0.x = fmaxf((acc[0] + sf[0]) * inv_r + bv0.x, 0.f);
    o0.y = fmaxf((acc[1] + sf[1]) * inv_r + bv0.y, 0.f);
    o0.z = fmaxf((acc[2] + sf[2]) * inv_r + bv0.z, 0.f);
    o0.w = fmaxf((acc[3] + sf[3]) * inv_r + bv0.w, 0.f);
    o1.x = fmaxf((acc[4] + sf[4]) * inv_r + bv1.x, 0.f);
    o1.y = fmaxf((acc[5] + sf[5]) * inv_r + bv1.y, 0.f);
    o1.z = fmaxf((acc[6] + sf[6]) * inv_r + bv1.z, 0.f);
    o1.w = fmaxf((acc[7] + sf[7]) * inv_r + bv1.w, 0.f);
    *(float4*)(out + (size_t)r * EMB + d8 * 8)     = o0;
    *(float4*)(out + (size_t)r * EMB + d8 * 8 + 4) = o1;
}

// ---- f32 fallback gather (if workspace too small for f16 copies) ----
__global__ void gather2f_kernel(const uint2* __restrict__ odU, const uint2* __restrict__ odI,
                                const int* __restrict__ colsU, const int* __restrict__ colsI,
                                const float* __restrict__ WU, const float* __restrict__ WI,
                                const float* __restrict__ bU, const float* __restrict__ bI,
                                const float* __restrict__ invU, const float* __restrict__ invI,
                                float* __restrict__ outU, float* __restrict__ outI, int ggU) {
    const uint2* od; const int* cols; const float* W; const float* bb; const float* inv;
    float* out; int n, r0;
    if ((int)blockIdx.x < ggU) { od = odU; cols = colsU; W = WU; bb = bU; inv = invU; out = outU; n = NUSERS; r0 = blockIdx.x * 32; }
    else                       { od = odI; cols = colsI; W = WI; bb = bI; inv = invI; out = outI; n = NITEMS; r0 = (blockIdx.x - ggU) * 32; }
    int r = r0 + (threadIdx.x >> 3);
    if (r >= n) return;
    int d8 = threadIdx.x & 7;
    uint2 o = od[r];
    unsigned k = o.x, end = o.x + o.y;
    const float* wb = W + d8 * 8;
    float acc[8] = {0.f, 0.f, 0.f, 0.f, 0.f, 0.f, 0.f, 0.f};
    for (; k < end; ++k) {
        int c0 = cols[k];
        float ic = inv[c0];
        float4 f0 = *(const float4*)(wb + (size_t)c0 * EMB);
        float4 f1 = *(const float4*)(wb + (size_t)c0 * EMB + 4);
        acc[0] += f0.x * ic; acc[1] += f0.y * ic; acc[2] += f0.z * ic; acc[3] += f0.w * ic;
        acc[4] += f1.x * ic; acc[5] += f1.y * ic; acc[6] += f1.z * ic; acc[7] += f1.w * ic;
    }
    float inv_r = inv[r];
    float4 s0 = *(const float4*)(W + (size_t)r * EMB + d8 * 8);
    float4 s1 = *(const float4*)(W + (size_t)r * EMB + d8 * 8 + 4);
    const float4 bv0 = *(const float4*)(bb + d8 * 8);
    const float4 bv1 = *(const float4*)(bb + d8 * 8 + 4);
    float4 o0, o1;
    o0.x = fmaxf((acc[0] + s0.x * inv_r) * inv_r + bv0.x, 0.f);
    o0.y = fmaxf((acc[1] + s0.y * inv_r) * inv_r + bv0.y, 0.f);
    o0.z = fmaxf((acc[2] + s0.z * inv_r) * inv_r + bv0.z, 0.f);
    o0.w = fmaxf((acc[3] + s0.w * inv_r) * inv_r + bv0.w, 0.f);
    o1.x = fmaxf((acc[4] + s1.x * inv_r) * inv_r + bv1.x, 0.f);
    o1.y = fmaxf((acc[5] + s1.y * inv_r) * inv_r + bv1.y, 0.f);
    o1.z = fmaxf((acc[6] + s1.z * inv_r) * inv_r + bv1.z, 0.f);
    o1.w = fmaxf((acc[7] + s1.w * inv_r) * inv_r + bv1.w, 0.f);
    *(float4*)(out + (size_t)r * EMB + d8 * 8)     = o0;
    *(float4*)(out + (size_t)r * EMB + d8 * 8 + 4) = o1;
}

extern "C" void kernel_launch(void* const* d_in, const int* in_sizes, int n_in,
                              void* d_out, int out_size, void* d_ws, size_t ws_size,
                              hipStream_t stream) {
    const int*   ue = (const int*)d_in[0];
    const int*   ie = (const int*)d_in[1];
    const float* Wu = (const float*)d_in[2];
    const float* bu = (const float*)d_in[3];
    const float* Wi = (const float*)d_in[4];
    const float* bi = (const float*)d_in[5];

    const int E_U = in_sizes[0] / 2;
    const int E_I = in_sizes[1] / 2;

    float* out_u = (float*)d_out;
    float* out_i = out_u + (size_t)NUSERS * EMB;

    // workspace layout (4-byte words); Wh overlays the dead pairs region
    unsigned* w       = (unsigned*)d_ws;
    unsigned* bcnt_u  = w;            w += MAXB;     // zeroed
    unsigned* bcnt_i  = w;            w += MAXB;     // zeroed
    unsigned* tot_u   = w;            w += 1;        // zeroed
    unsigned* tot_i   = w;            w += 1;        // zeroed
    uint2*    od_u    = (uint2*)w;    w += 2 * (size_t)NUSERS;
    uint2*    od_i    = (uint2*)w;    w += 2 * (size_t)NITEMS;
    float*    inv_u   = (float*)w;    w += NUSERS;
    float*    inv_i   = (float*)w;    w += NITEMS;
    int*      cols_u  = (int*)w;      w += E_U;
    int*      cols_i  = (int*)w;      w += E_I;
    w += (size_t)(-(intptr_t)(w - (unsigned*)d_ws)) & 3;   // align to 16 B
    // union region: pairs (build phase) / Wh (gather phase)
    unsigned* un      = w;
    unsigned* pairs_u = un;                            // NB_U*CAP words
    unsigned* pairs_i = un + (size_t)NB_U * CAP;       // NB_I*CAP words
    __half*   wh_u    = (__half*)un;                   // NUSERS*EMB halfs
    __half*   wh_i    = (__half*)un + (size_t)NUSERS * EMB;
    size_t un_words_pairs = (size_t)(NB_U + NB_I) * CAP;
    size_t un_words_wh    = (size_t)(NUSERS + NITEMS) * EMB / 2;
    size_t un_words = un_words_pairs > un_words_wh ? un_words_pairs : un_words_wh;
    const size_t need_bytes = (size_t)((char*)(un + un_words) - (char*)d_ws);
    const bool use_half = (ws_size >= need_bytes);

    hipMemsetAsync(bcnt_u, 0, (2 * MAXB + 2) * sizeof(unsigned), stream);

    const int gb_u = (E_U + CHUNK - 1) / CHUNK;  // 293
    const int gb_i = (E_I + CHUNK - 1) / CHUNK;  // 147
    const int gg_u = (NUSERS + 31) / 32;         // 3125
    const int gg_i = (NITEMS + 31) / 32;         // 1563

    bscatter2_kernel<<<gb_u + gb_i, 256, 0, stream>>>(ue, ie, bcnt_u, bcnt_i,
                                                      pairs_u, pairs_i, E_U, E_I, gb_u);
    bprep_kernel    <<<NB_U + NB_I, 256, 0, stream>>>(bcnt_u, bcnt_i, pairs_u, pairs_i,
                                                      od_u, od_i, inv_u, inv_i,
                                                      cols_u, cols_i, tot_u, tot_i);
    if (use_half) {
        const int tot4 = (NUSERS + NITEMS) * EMB / 4;
        tohalf2_kernel <<<(tot4 + 255) / 256, 256, 0, stream>>>(Wu, Wi, inv_u, inv_i, wh_u, wh_i);
        gather2h_kernel<<<gg_u + gg_i, 256, 0, stream>>>(od_u, od_i, cols_u, cols_i,
                                                         wh_u, wh_i, bu, bi, inv_u, inv_i,
                                                         out_u, out_i, gg_u);
    } else {
        gather2f_kernel<<<gg_u + gg_i, 256, 0, stream>>>(od_u, od_i, cols_u, cols_i,
                                                         Wu, Wi, bu, bi, inv_u, inv_i,
                                                         out_u, out_i, gg_u);
    }
}

// Round 10
// 116.846 us; speedup vs baseline: 1.2485x; 1.1103x over previous
//
#include <hip/hip_runtime.h>
#include <hip/hip_fp16.h>

#define NUSERS 100000
#define NITEMS 50000
#define EMB 64
#define BROWS 512       // rows per bucket
#define CHUNK 4096      // edges per block in scatter pass
#define MAXB 256        // max buckets (user: 196, item: 98)
#define CAP  8192       // padded bucket capacity (mean ~6.1K, ~26 sigma headroom)
#define NTOH 1024       // tohalf rider blocks inside build1
#define NB_U ((NUSERS + BROWS - 1) / BROWS)   // 196
#define NB_I ((NITEMS + BROWS - 1) / BROWS)   // 98

// packed pair: (local_row << 20) | col   (local_row < 512, col < 2^17)

// ---- launch 1: bucketed scatter (blocks < gbTot) + f32->f16 cast riders ----
__global__ void build1_kernel(const int* __restrict__ rowU, const int* __restrict__ rowI,
                              unsigned* __restrict__ bcntU, unsigned* __restrict__ bcntI,
                              unsigned* __restrict__ pairsU, unsigned* __restrict__ pairsI,
                              const float* __restrict__ WU, const float* __restrict__ WI,
                              __half* __restrict__ WhU, __half* __restrict__ WhI,
                              int EU, int EI, int gbU, int gbTot) {
    __shared__ unsigned h[MAXB];
    __shared__ unsigned base[MAXB];
    __shared__ int rstage[CHUNK];
    int t = threadIdx.x;
    if ((int)blockIdx.x >= gbTot) {
        // rider: unscaled f32 -> f16 stream conversion (independent of scatter)
        int nt = (int)gridDim.x - gbTot;
        const int T4U = NUSERS * (EMB / 4), T4I = NITEMS * (EMB / 4);
        for (int i = ((int)blockIdx.x - gbTot) * 256 + t; i < T4U + T4I; i += nt * 256) {
            const float4* W; __half2* Wh2; int idx;
            if (i < T4U) { W = (const float4*)WU; Wh2 = (__half2*)WhU; idx = i; }
            else         { W = (const float4*)WI; Wh2 = (__half2*)WhI; idx = i - T4U; }
            float4 w = W[idx];
            Wh2[2 * idx]     = __floats2half2_rn(w.x, w.y);
            Wh2[2 * idx + 1] = __floats2half2_rn(w.z, w.w);
        }
        return;
    }
    const int* row; const int* col; unsigned* bcnt; unsigned* pairs; int E, blk;
    if ((int)blockIdx.x < gbU) { row = rowU; col = rowU + EU; bcnt = bcntU; pairs = pairsU; E = EU; blk = blockIdx.x; }
    else                       { row = rowI; col = rowI + EI; bcnt = bcntI; pairs = pairsI; E = EI; blk = blockIdx.x - gbU; }
    for (int i = t; i < MAXB; i += 256) h[i] = 0;
    __syncthreads();
    int lo = blk * CHUNK, hi = min(lo + CHUNK, E);
    for (int i = lo + t; i < hi; i += 256) {
        int r = row[i];
        rstage[i - lo] = r;
        atomicAdd(&h[r >> 9], 1u);
    }
    __syncthreads();
    for (int i = t; i < MAXB; i += 256) {
        unsigned cnt = h[i];
        base[i] = cnt ? ((unsigned)i * CAP + atomicAdd(&bcnt[i], cnt)) : 0u;
        h[i] = 0;
    }
    __syncthreads();
    for (int i = lo + t; i < hi; i += 256) {
        int r = rstage[i - lo];
        int b = r >> 9;
        unsigned p = base[b] + atomicAdd(&h[b], 1u);
        pairs[p] = ((unsigned)(r & 511) << 20) | (unsigned)col[i];
    }
}

// ---- launch 2: per-bucket degree + inv + scan + base alloc + fill (pairs staged in LDS) ----
__global__ void bprep_kernel(const unsigned* __restrict__ bcntU, const unsigned* __restrict__ bcntI,
                             const unsigned* __restrict__ pairsU, const unsigned* __restrict__ pairsI,
                             uint2* __restrict__ odU, uint2* __restrict__ odI,
                             float* __restrict__ invU, float* __restrict__ invI,
                             int* __restrict__ colsU, int* __restrict__ colsI,
                             unsigned* __restrict__ totU, unsigned* __restrict__ totI) {
    __shared__ unsigned d[BROWS];
    __shared__ unsigned cur[BROWS];
    __shared__ unsigned sh[256];
    __shared__ unsigned stage[CAP];
    __shared__ unsigned sbase;
    const unsigned* bcnt; const unsigned* pairs; uint2* od; float* inv; int* cols; unsigned* tot; int n, b;
    if ((int)blockIdx.x < NB_U) { bcnt = bcntU; pairs = pairsU; od = odU; inv = invU; cols = colsU; tot = totU; n = NUSERS; b = blockIdx.x; }
    else                        { bcnt = bcntI; pairs = pairsI; od = odI; inv = invI; cols = colsI; tot = totI; n = NITEMS; b = blockIdx.x - NB_U; }
    int t = threadIdx.x;
    int rbase = b * BROWS;
    for (int i = t; i < BROWS; i += 256) d[i] = 0;
    __syncthreads();
    unsigned cnt = min(bcnt[b], (unsigned)CAP);
    unsigned lo = (unsigned)b * CAP;
    for (unsigned i = t; i < cnt; i += 256) {
        unsigned pk = pairs[lo + i];
        stage[i] = pk;
        atomicAdd(&d[pk >> 20], 1u);
    }
    __syncthreads();
    unsigned v0 = d[2 * t], v1 = d[2 * t + 1];
    unsigned s = v0 + v1;
    sh[t] = s;
    __syncthreads();
    for (int off = 1; off < 256; off <<= 1) {
        unsigned add = (t >= off) ? sh[t - off] : 0u;
        __syncthreads();
        sh[t] += add;
        __syncthreads();
    }
    if (t == 255) sbase = atomicAdd(tot, sh[255]);   // bucket's base in cols[]
    __syncthreads();
    unsigned running = sbase + sh[t] - s;
    int i0 = rbase + 2 * t, i1 = i0 + 1;
    if (i0 < n) { od[i0] = make_uint2(running, v0); inv[i0] = rsqrtf((float)(v0 + 1u)); cur[2 * t]     = running; running += v0; }
    if (i1 < n) { od[i1] = make_uint2(running, v1); inv[i1] = rsqrtf((float)(v1 + 1u)); cur[2 * t + 1] = running; running += v1; }
    __syncthreads();
    for (unsigned i = t; i < cnt; i += 256) {
        unsigned pk = stage[i];
        unsigned p = atomicAdd(&cur[pk >> 20], 1u);
        cols[p] = (int)(pk & 0xFFFFFu);
    }
}

// ---- standalone f32->f16 cast (Path B: Wh overlays dead pairs, runs after bprep) ----
__global__ void tohalf_kernel(const float* __restrict__ WU, const float* __restrict__ WI,
                              __half* __restrict__ WhU, __half* __restrict__ WhI) {
    const int T4U = NUSERS * (EMB / 4), T4I = NITEMS * (EMB / 4);
    for (int i = blockIdx.x * 256 + threadIdx.x; i < T4U + T4I; i += gridDim.x * 256) {
        const float4* W; __half2* Wh2; int idx;
        if (i < T4U) { W = (const float4*)WU; Wh2 = (__half2*)WhU; idx = i; }
        else         { W = (const float4*)WI; Wh2 = (__half2*)WhI; idx = i - T4U; }
        float4 w = W[idx];
        Wh2[2 * idx]     = __floats2half2_rn(w.x, w.y);
        Wh2[2 * idx + 1] = __floats2half2_rn(w.z, w.w);
    }
}

__device__ __forceinline__ void accs(float* acc, float4 f, float ic) {
    const __half2* h = (const __half2*)&f;
    #pragma unroll
    for (int j = 0; j < 4; j++) {
        float2 tv = __half22float2(h[j]);
        acc[2 * j]     += tv.x * ic;
        acc[2 * j + 1] += tv.y * ic;
    }
}

// ---- gather, unscaled f16 + inv[c]: 8 lanes/row, 8 sequential rows/wave, 4-way unroll ----
__global__ void gather2h_kernel(const uint2* __restrict__ odU, const uint2* __restrict__ odI,
                                const int* __restrict__ colsU, const int* __restrict__ colsI,
                                const __half* __restrict__ WhU, const __half* __restrict__ WhI,
                                const float* __restrict__ bU, const float* __restrict__ bI,
                                const float* __restrict__ invU, const float* __restrict__ invI,
                                float* __restrict__ outU, float* __restrict__ outI, int ggU) {
    const uint2* od; const int* cols; const __half* Wh; const float* bb; const float* inv;
    float* out; int n, r0;
    if ((int)blockIdx.x < ggU) { od = odU; cols = colsU; Wh = WhU; bb = bU; inv = invU; out = outU; n = NUSERS; r0 = blockIdx.x * 32; }
    else                       { od = odI; cols = colsI; Wh = WhI; bb = bI; inv = invI; out = outI; n = NITEMS; r0 = (blockIdx.x - ggU) * 32; }
    int r = r0 + (threadIdx.x >> 3);
    if (r >= n) return;
    int d8 = threadIdx.x & 7;
    uint2 o = od[r];
    unsigned k = o.x, end = o.x + o.y;
    const __half* wb = Wh + d8 * 8;
    float acc[8] = {0.f, 0.f, 0.f, 0.f, 0.f, 0.f, 0.f, 0.f};
    for (; k + 4 <= end; k += 4) {
        int c0 = cols[k];
        int c1 = cols[k + 1];
        int c2 = cols[k + 2];
        int c3 = cols[k + 3];
        float i0 = inv[c0], i1 = inv[c1], i2 = inv[c2], i3 = inv[c3];
        float4 f0 = *(const float4*)(wb + (size_t)c0 * EMB);
        float4 f1 = *(const float4*)(wb + (size_t)c1 * EMB);
        float4 f2 = *(const float4*)(wb + (size_t)c2 * EMB);
        float4 f3 = *(const float4*)(wb + (size_t)c3 * EMB);
        accs(acc, f0, i0); accs(acc, f1, i1); accs(acc, f2, i2); accs(acc, f3, i3);
    }
    for (; k < end; ++k) {
        int c0 = cols[k];
        float i0 = inv[c0];
        float4 f0 = *(const float4*)(wb + (size_t)c0 * EMB);
        accs(acc, f0, i0);
    }
    // epilogue: out = relu((acc + W[r]*inv_r) * inv_r + b)
    float inv_r = inv[r];
    float4 fs = *(const float4*)(Wh + (size_t)r * EMB + d8 * 8);
    accs(acc, fs, inv_r);
    const float4 bv0 = *(const float4*)(bb + d8 * 8);
    const float4 bv1 = *(const float4*)(bb + d8 * 8 + 4);
    float4 o0, o1;
    o0.x = fmaxf(acc[0] * inv_r + bv0.x, 0.f);
    o0.y = fmaxf(acc[1] * inv_r + bv0.y, 0.f);
    o0.z = fmaxf(acc[2] * inv_r + bv0.z, 0.f);
    o0.w = fmaxf(acc[3] * inv_r + bv0.w, 0.f);
    o1.x = fmaxf(acc[4] * inv_r + bv1.x, 0.f);
    o1.y = fmaxf(acc[5] * inv_r + bv1.y, 0.f);
    o1.z = fmaxf(acc[6] * inv_r + bv1.z, 0.f);
    o1.w = fmaxf(acc[7] * inv_r + bv1.w, 0.f);
    *(float4*)(out + (size_t)r * EMB + d8 * 8)     = o0;
    *(float4*)(out + (size_t)r * EMB + d8 * 8 + 4) = o1;
}

// ---- f32 fallback gather (if workspace too small for any f16 copy) ----
__global__ void gather2f_kernel(const uint2* __restrict__ odU, const uint2* __restrict__ odI,
                                const int* __restrict__ colsU, const int* __restrict__ colsI,
                                const float* __restrict__ WU, const float* __restrict__ WI,
                                const float* __restrict__ bU, const float* __restrict__ bI,
                                const float* __restrict__ invU, const float* __restrict__ invI,
                                float* __restrict__ outU, float* __restrict__ outI, int ggU) {
    const uint2* od; const int* cols; const float* W; const float* bb; const float* inv;
    float* out; int n, r0;
    if ((int)blockIdx.x < ggU) { od = odU; cols = colsU; W = WU; bb = bU; inv = invU; out = outU; n = NUSERS; r0 = blockIdx.x * 32; }
    else                       { od = odI; cols = colsI; W = WI; bb = bI; inv = invI; out = outI; n = NITEMS; r0 = (blockIdx.x - ggU) * 32; }
    int r = r0 + (threadIdx.x >> 3);
    if (r >= n) return;
    int d8 = threadIdx.x & 7;
    uint2 o = od[r];
    unsigned k = o.x, end = o.x + o.y;
    const float* wb = W + d8 * 8;
    float acc[8] = {0.f, 0.f, 0.f, 0.f, 0.f, 0.f, 0.f, 0.f};
    for (; k < end; ++k) {
        int c0 = cols[k];
        float ic = inv[c0];
        float4 f0 = *(const float4*)(wb + (size_t)c0 * EMB);
        float4 f1 = *(const float4*)(wb + (size_t)c0 * EMB + 4);
        acc[0] += f0.x * ic; acc[1] += f0.y * ic; acc[2] += f0.z * ic; acc[3] += f0.w * ic;
        acc[4] += f1.x * ic; acc[5] += f1.y * ic; acc[6] += f1.z * ic; acc[7] += f1.w * ic;
    }
    float inv_r = inv[r];
    float4 s0 = *(const float4*)(W + (size_t)r * EMB + d8 * 8);
    float4 s1 = *(const float4*)(W + (size_t)r * EMB + d8 * 8 + 4);
    const float4 bv0 = *(const float4*)(bb + d8 * 8);
    const float4 bv1 = *(const float4*)(bb + d8 * 8 + 4);
    float4 o0, o1;
    o0.x = fmaxf((acc[0] + s0.x * inv_r) * inv_r + bv0.x, 0.f);
    o0.y = fmaxf((acc[1] + s0.y * inv_r) * inv_r + bv0.y, 0.f);
    o0.z = fmaxf((acc[2] + s0.z * inv_r) * inv_r + bv0.z, 0.f);
    o0.w = fmaxf((acc[3] + s0.w * inv_r) * inv_r + bv0.w, 0.f);
    o1.x = fmaxf((acc[4] + s1.x * inv_r) * inv_r + bv1.x, 0.f);
    o1.y = fmaxf((acc[5] + s1.y * inv_r) * inv_r + bv1.y, 0.f);
    o1.z = fmaxf((acc[6] + s1.z * inv_r) * inv_r + bv1.z, 0.f);
    o1.w = fmaxf((acc[7] + s1.w * inv_r) * inv_r + bv1.w, 0.f);
    *(float4*)(out + (size_t)r * EMB + d8 * 8)     = o0;
    *(float4*)(out + (size_t)r * EMB + d8 * 8 + 4) = o1;
}

extern "C" void kernel_launch(void* const* d_in, const int* in_sizes, int n_in,
                              void* d_out, int out_size, void* d_ws, size_t ws_size,
                              hipStream_t stream) {
    const int*   ue = (const int*)d_in[0];
    const int*   ie = (const int*)d_in[1];
    const float* Wu = (const float*)d_in[2];
    const float* bu = (const float*)d_in[3];
    const float* Wi = (const float*)d_in[4];
    const float* bi = (const float*)d_in[5];

    const int E_U = in_sizes[0] / 2;
    const int E_I = in_sizes[1] / 2;

    float* out_u = (float*)d_out;
    float* out_i = out_u + (size_t)NUSERS * EMB;

    // workspace layout (4-byte words)
    unsigned* w       = (unsigned*)d_ws;
    unsigned* bcnt_u  = w;            w += MAXB;     // zeroed
    unsigned* bcnt_i  = w;            w += MAXB;     // zeroed
    unsigned* tot_u   = w;            w += 1;        // zeroed
    unsigned* tot_i   = w;            w += 1;        // zeroed
    uint2*    od_u    = (uint2*)w;    w += 2 * (size_t)NUSERS;
    uint2*    od_i    = (uint2*)w;    w += 2 * (size_t)NITEMS;
    float*    inv_u   = (float*)w;    w += NUSERS;
    float*    inv_i   = (float*)w;    w += NITEMS;
    int*      cols_u  = (int*)w;      w += E_U;
    int*      cols_i  = (int*)w;      w += E_I;
    w += (size_t)(-(intptr_t)(w - (unsigned*)d_ws)) & 3;   // align to 16 B

    const size_t pairs_words = (size_t)(NB_U + NB_I) * CAP;
    const size_t wh_words    = (size_t)(NUSERS + NITEMS) * EMB / 2;
    unsigned* pairs_u = w;
    unsigned* pairs_i = w + (size_t)NB_U * CAP;
    // Path A: Wh in its own region (concurrent with pairs). Path B: Wh overlays pairs.
    const size_t need_A = (size_t)((char*)(w + pairs_words + wh_words) - (char*)d_ws);
    const size_t need_B = (size_t)((char*)(w + (pairs_words > wh_words ? pairs_words : wh_words)) - (char*)d_ws);
    const bool pathA = (ws_size >= need_A);
    const bool pathB = (!pathA && ws_size >= need_B);
    __half* wh_u = pathA ? (__half*)(w + pairs_words) : (__half*)w;
    __half* wh_i = wh_u + (size_t)NUSERS * EMB;

    hipMemsetAsync(bcnt_u, 0, (2 * MAXB + 2) * sizeof(unsigned), stream);

    const int gb_u  = (E_U + CHUNK - 1) / CHUNK;  // 293
    const int gb_i  = (E_I + CHUNK - 1) / CHUNK;  // 147
    const int gbTot = gb_u + gb_i;
    const int gg_u  = (NUSERS + 31) / 32;         // 3125
    const int gg_i  = (NITEMS + 31) / 32;         // 1563

    if (pathA) {
        build1_kernel <<<gbTot + NTOH, 256, 0, stream>>>(ue, ie, bcnt_u, bcnt_i, pairs_u, pairs_i,
                                                         Wu, Wi, wh_u, wh_i, E_U, E_I, gb_u, gbTot);
        bprep_kernel  <<<NB_U + NB_I, 256, 0, stream>>>(bcnt_u, bcnt_i, pairs_u, pairs_i,
                                                        od_u, od_i, inv_u, inv_i,
                                                        cols_u, cols_i, tot_u, tot_i);
        gather2h_kernel<<<gg_u + gg_i, 256, 0, stream>>>(od_u, od_i, cols_u, cols_i,
                                                         wh_u, wh_i, bu, bi, inv_u, inv_i,
                                                         out_u, out_i, gg_u);
    } else if (pathB) {
        build1_kernel <<<gbTot, 256, 0, stream>>>(ue, ie, bcnt_u, bcnt_i, pairs_u, pairs_i,
                                                  Wu, Wi, wh_u, wh_i, E_U, E_I, gb_u, gbTot);
        bprep_kernel  <<<NB_U + NB_I, 256, 0, stream>>>(bcnt_u, bcnt_i, pairs_u, pairs_i,
                                                        od_u, od_i, inv_u, inv_i,
                                                        cols_u, cols_i, tot_u, tot_i);
        tohalf_kernel <<<2048, 256, 0, stream>>>(Wu, Wi, wh_u, wh_i);
        gather2h_kernel<<<gg_u + gg_i, 256, 0, stream>>>(od_u, od_i, cols_u, cols_i,
                                                         wh_u, wh_i, bu, bi, inv_u, inv_i,
                                                         out_u, out_i, gg_u);
    } else {
        build1_kernel <<<gbTot, 256, 0, stream>>>(ue, ie, bcnt_u, bcnt_i, pairs_u, pairs_i,
                                                  Wu, Wi, (__half*)nullptr, (__half*)nullptr,
                                                  E_U, E_I, gb_u, gbTot);
        bprep_kernel  <<<NB_U + NB_I, 256, 0, stream>>>(bcnt_u, bcnt_i, pairs_u, pairs_i,
                                                        od_u, od_i, inv_u, inv_i,
                                                        cols_u, cols_i, tot_u, tot_i);
        gather2f_kernel<<<gg_u + gg_i, 256, 0, stream>>>(od_u, od_i, cols_u, cols_i,
                                                         Wu, Wi, bu, bi, inv_u, inv_i,
                                                         out_u, out_i, gg_u);
    }
}